// Round 15
// baseline (51.844 us; speedup 1.0000x reference)
//
#include <hip/hip_runtime.h>
#include <hip/hip_bf16.h>

// PIXOR feature layer:
//   intensity[n] = mean_t vox_feats[n, t, 4]
//   out[b, 0, y, x] = 1.0   (occupancy)
//   out[b, 1, y, x] = intensity[n_last]  (last duplicate wins == max n wins)
//
// 2-dispatch structure (votes in ws, disjoint from out, so zero + vote fuse):
//   k1 (one 64-row tile per block, grid = ceil(N/64)):
//       - grid-stride zero(out) with inline-asm global_store_dwordx4 nt
//         (non-temporal: out is write-only; keeping its 71.7 MB from
//         write-allocating in L3 should leave the 128 MB vox tensor fully
//         L3-resident across replays. R10's NT regression used the builtin;
//         this forces one wide nt store via a true vector-register type.)
//       - tile-coalesced intensity: waves read 64 CONSECUTIVE float4s
//         (1 KB contiguous); ch4 elements scatter to unique LDS slots,
//         4-lane reduce per row
//       - packed 8B rec (cell<<32 | inten bits) + idempotent max-CAS vote
//         (key = n+1) into ws_vote
//   k2: read rec (plain; cross-dispatch plain-to-plain is safe), coherent
//       vote read via atomicAdd(cell,0) (atomic-written data needs an atomic
//       read across dispatches — R3 stale-L2 bug); unique winner PLAIN-stores
//       occ=1.0 + intensity (scattered 4B stores stay on the cached path).

#define PX_NY 800
#define PX_NX 700
#define PX_P  (PX_NY * PX_NX)      // 560000 (compile-time: magic-mul for /P)
#define PX_T  32
#define PX_C  5
#define ROW_F4 40                  // float4s per voxel row (160 floats / 4)
#define TILE   64                  // rows per block
#define TILE_F4 (TILE * ROW_F4)    // 2560 float4s per tile
#define LPAD   33                  // padded LDS row stride (floats)

typedef float f32x4 __attribute__((ext_vector_type(4)));

__device__ __forceinline__ void nt_store_f4(f32x4* p, f32x4 v) {
    asm volatile("global_store_dwordx4 %0, %1, off nt"
                 :
                 : "v"(p), "v"(v)
                 : "memory");
}

__global__ void __launch_bounds__(256)
pixor_k1(const float4*       __restrict__ vox4,
         const int4*         __restrict__ coords4,
         unsigned long long* __restrict__ rec,     // (cell<<32)|f32bits
         unsigned int*       __restrict__ vote,
         f32x4*              __restrict__ out4,
         int N, int zq) {
    __shared__ float lsl[TILE * LPAD];   // [row][t] ch4 values, padded

    const int tid  = threadIdx.x;
    const int gtid = blockIdx.x * 256 + tid;
    const int nth  = gridDim.x * 256;
    const int t    = blockIdx.x;          // tile index
    const int base   = t * TILE_F4;
    const int totF4  = N * ROW_F4;

    // ---- zero the output: wide NT stores, bypass L3 allocation ----
    const f32x4 z = {0.f, 0.f, 0.f, 0.f};
    for (int i = gtid; i < zq; i += nth)
        nt_store_f4(&out4[i], z);

    // ---- tile load: waves of 64 consecutive float4s (1 KB contiguous) ----
#pragma unroll
    for (int k = 0; k < 10; ++k) {
        int i  = k * 256 + tid;           // 0..2559 within tile
        int gi = base + i;
        if (gi < totF4) {
            float4 f = vox4[gi];
            int row = i / ROW_F4;         // 0..63
            int j   = i - row * ROW_F4;   // float4 index within row
            int sub = j % 5;              // 0 -> carries no ch4 element
            if (sub) {
                float v = (sub == 1) ? f.x
                        : (sub == 2) ? f.y
                        : (sub == 3) ? f.z : f.w;
                int tp = (4 * j + (sub - 1) - 4) / 5;   // point idx 0..31
                lsl[row * LPAD + tp] = v; // unique slot: no atomics
            }
        }
    }
    __syncthreads();

    // ---- reduce: 4 lanes per row, 8 values each, then 2-step shuffle ----
    int row = tid >> 2, q = tid & 3;
    const float* rp = &lsl[row * LPAD + q * 8];
    float s = 0.f;
#pragma unroll
    for (int m = 0; m < 8; ++m) s += rp[m];
    s += __shfl_xor(s, 1);
    s += __shfl_xor(s, 2);

    int grow = t * TILE + row;
    if (q == 0 && grow < N) {
        float inten = s * (1.0f / (float)PX_T);

        int4 c4 = coords4[grow];          // (b, z, y, x)
        unsigned cell = (unsigned)(c4.x * PX_P + c4.z * PX_NX + c4.w);
        unsigned key  = (unsigned)(grow + 1);

        rec[grow] = ((unsigned long long)cell << 32) |
                    (unsigned long long)__float_as_uint(inten);

        // idempotent max-CAS vote; anything outside [1,N] (0xAA poison,
        // zeros) is garbage and gets replaced; leftover finals are maxima
        unsigned old = atomicCAS(vote + cell, 0u, key);
        while (old != 0u) {
            if ((old - 1u) < (unsigned)N && old >= key) break;
            unsigned prev = atomicCAS(vote + cell, old, key);
            if (prev == old) break;
            old = prev;
        }
    }
}

__global__ void __launch_bounds__(256)
pixor_k2(const unsigned long long* __restrict__ rec,
         unsigned int*             __restrict__ vote,
         float*                    __restrict__ out,
         int N) {
    int n = blockIdx.x * 256 + threadIdx.x;
    if (n >= N) return;

    unsigned long long r = rec[n];            // plain read: k1 plain-stored it
    unsigned cell = (unsigned)(r >> 32);

    // coherent, non-destructive vote read (leaves buffer idempotent)
    unsigned v = atomicAdd(vote + cell, 0u);
    if (v == (unsigned)(n + 1)) {             // unique winner
        unsigned b    = cell / (unsigned)PX_P;           // magic-mul
        unsigned base = cell + b * (unsigned)PX_P;       // = b*2P + yx
        out[base]        = 1.0f;                         // occupancy
        out[base + PX_P] = __uint_as_float((unsigned)r); // intensity
    }
}

extern "C" void kernel_launch(void* const* d_in, const int* in_sizes, int n_in,
                              void* d_out, int out_size, void* d_ws, size_t ws_size,
                              hipStream_t stream) {
    const float* vox    = (const float*)d_in[0];   // [N, 32, 5] f32
    const int*   coords = (const int*)d_in[2];     // [N, 4] i32 (b, z, y, x)
    float* out = (float*)d_out;

    const int N  = in_sizes[1];                    // 200000
    const int B  = out_size / (2 * PX_P);          // 16
    const int zq = out_size / 4;                   // float4s to zero

    unsigned int*       ws_vote = (unsigned int*)d_ws;             // B*P uints
    unsigned long long* ws_rec  =
        (unsigned long long*)((unsigned int*)d_ws + (size_t)B * PX_P + 32);

    const int BLK = 256;
    const int ntiles = (N + TILE - 1) / TILE;      // 3125: one tile per block

    pixor_k1<<<ntiles, BLK, 0, stream>>>((const float4*)vox, (const int4*)coords,
                                         ws_rec, ws_vote, (f32x4*)out,
                                         N, zq);

    pixor_k2<<<(N + BLK - 1) / BLK, BLK, 0, stream>>>(ws_rec, ws_vote, out, N);
}

// Round 16
// 51.023 us; speedup vs baseline: 1.0161x; 1.0161x over previous
//
#include <hip/hip_runtime.h>
#include <hip/hip_bf16.h>

// PIXOR feature layer:
//   intensity[n] = mean_t vox_feats[n, t, 4]
//   out[b, 0, y, x] = 1.0   (occupancy)
//   out[b, 1, y, x] = intensity[n_last]  (last duplicate wins == max n wins)
//
// 2-dispatch structure (votes in ws, disjoint from out, so zero + vote fuse):
//   k1 (one 64-row tile per block, grid = ceil(N/64)):
//       - tile loads and zero(out) stores INTERLEAVED 1:1 (both VMEM streams
//         in flight from the start; R9 = stores-first and R12 = loads-first
//         both measured ~45.5 — this is the remaining scheduling variant)
//       - waves read 64 CONSECUTIVE float4s (1 KB contiguous); ch4 elements
//         scatter to unique LDS slots (no atomics), 4-lane reduce per row
//       - packed 8B rec (cell<<32 | inten bits) + idempotent max-CAS vote
//         (key = n+1) into ws_vote
//   k2: read rec (plain; cross-dispatch plain-to-plain is safe), coherent
//       vote read via atomicAdd(cell,0) (atomic-written data needs an atomic
//       read across dispatches — R3 stale-L2 bug); unique winner plain-stores
//       occ=1.0 + intensity over k1's zeros (verified store-after-store).

#define PX_NY 800
#define PX_NX 700
#define PX_P  (PX_NY * PX_NX)      // 560000 (compile-time: magic-mul for /P)
#define PX_T  32
#define PX_C  5
#define ROW_F4 40                  // float4s per voxel row (160 floats / 4)
#define TILE   64                  // rows per block
#define TILE_F4 (TILE * ROW_F4)    // 2560 float4s per tile
#define LPAD   33                  // padded LDS row stride (floats)

__global__ void __launch_bounds__(256)
pixor_k1(const float4*       __restrict__ vox4,
         const int4*         __restrict__ coords4,
         unsigned long long* __restrict__ rec,     // (cell<<32)|f32bits
         unsigned int*       __restrict__ vote,
         float4*             __restrict__ out4,
         int N, int zq) {
    __shared__ float lsl[TILE * LPAD];   // [row][t] ch4 values, padded

    const int tid  = threadIdx.x;
    const int gtid = blockIdx.x * 256 + tid;
    const int nth  = gridDim.x * 256;
    const int t    = blockIdx.x;          // tile index
    const int base   = t * TILE_F4;
    const int totF4  = N * ROW_F4;

    const float4 z = make_float4(0.f, 0.f, 0.f, 0.f);

    // ---- interleaved: issue load k, then zero-store slot k ----
    float4 f[10];
#pragma unroll
    for (int k = 0; k < 10; ++k) {
        int gi = base + k * 256 + tid;
        f[k] = (gi < totF4) ? vox4[gi] : z;
        int zi = gtid + k * nth;          // 10 slots cover zq (4.48M < 8M)
        if (zi < zq) out4[zi] = z;
    }

    // ---- scatter ch4 elements to unique LDS slots ----
#pragma unroll
    for (int k = 0; k < 10; ++k) {
        int i   = k * 256 + tid;          // 0..2559 within tile
        int row = i / ROW_F4;             // 0..63
        int j   = i - row * ROW_F4;       // float4 index within row
        int sub = j % 5;                  // 0 -> carries no ch4 element
        if (sub) {
            float v = (sub == 1) ? f[k].x
                    : (sub == 2) ? f[k].y
                    : (sub == 3) ? f[k].z : f[k].w;
            int tp = (4 * j + (sub - 1) - 4) / 5;   // point idx 0..31
            lsl[row * LPAD + tp] = v;     // unique slot: no atomics
        }
    }
    __syncthreads();

    // ---- reduce: 4 lanes per row, 8 values each, then 2-step shuffle ----
    int row = tid >> 2, q = tid & 3;
    const float* rp = &lsl[row * LPAD + q * 8];
    float s = 0.f;
#pragma unroll
    for (int m = 0; m < 8; ++m) s += rp[m];
    s += __shfl_xor(s, 1);
    s += __shfl_xor(s, 2);

    int grow = t * TILE + row;
    if (q == 0 && grow < N) {
        float inten = s * (1.0f / (float)PX_T);

        int4 c4 = coords4[grow];          // (b, z, y, x)
        unsigned cell = (unsigned)(c4.x * PX_P + c4.z * PX_NX + c4.w);
        unsigned key  = (unsigned)(grow + 1);

        rec[grow] = ((unsigned long long)cell << 32) |
                    (unsigned long long)__float_as_uint(inten);

        // idempotent max-CAS vote; anything outside [1,N] (0xAA poison,
        // zeros) is garbage and gets replaced; leftover finals are maxima
        unsigned old = atomicCAS(vote + cell, 0u, key);
        while (old != 0u) {
            if ((old - 1u) < (unsigned)N && old >= key) break;
            unsigned prev = atomicCAS(vote + cell, old, key);
            if (prev == old) break;
            old = prev;
        }
    }
}

__global__ void __launch_bounds__(256)
pixor_k2(const unsigned long long* __restrict__ rec,
         unsigned int*             __restrict__ vote,
         float*                    __restrict__ out,
         int N) {
    int n = blockIdx.x * 256 + threadIdx.x;
    if (n >= N) return;

    unsigned long long r = rec[n];            // plain read: k1 plain-stored it
    unsigned cell = (unsigned)(r >> 32);

    // coherent, non-destructive vote read (leaves buffer idempotent)
    unsigned v = atomicAdd(vote + cell, 0u);
    if (v == (unsigned)(n + 1)) {             // unique winner
        unsigned b    = cell / (unsigned)PX_P;           // magic-mul
        unsigned base = cell + b * (unsigned)PX_P;       // = b*2P + yx
        out[base]        = 1.0f;                         // occupancy
        out[base + PX_P] = __uint_as_float((unsigned)r); // intensity
    }
}

extern "C" void kernel_launch(void* const* d_in, const int* in_sizes, int n_in,
                              void* d_out, int out_size, void* d_ws, size_t ws_size,
                              hipStream_t stream) {
    const float* vox    = (const float*)d_in[0];   // [N, 32, 5] f32
    const int*   coords = (const int*)d_in[2];     // [N, 4] i32 (b, z, y, x)
    float* out = (float*)d_out;

    const int N  = in_sizes[1];                    // 200000
    const int B  = out_size / (2 * PX_P);          // 16
    const int zq = out_size / 4;                   // float4s to zero

    unsigned int*       ws_vote = (unsigned int*)d_ws;             // B*P uints
    unsigned long long* ws_rec  =
        (unsigned long long*)((unsigned int*)d_ws + (size_t)B * PX_P + 32);

    const int BLK = 256;
    const int ntiles = (N + TILE - 1) / TILE;      // 3125: one tile per block

    pixor_k1<<<ntiles, BLK, 0, stream>>>((const float4*)vox, (const int4*)coords,
                                         ws_rec, ws_vote, (float4*)out,
                                         N, zq);

    pixor_k2<<<(N + BLK - 1) / BLK, BLK, 0, stream>>>(ws_rec, ws_vote, out, N);
}

// Round 17
// 45.164 us; speedup vs baseline: 1.1479x; 1.1297x over previous
//
#include <hip/hip_runtime.h>
#include <hip/hip_bf16.h>

// PIXOR feature layer (best-measured variant, R9 = 45.37 us):
//   intensity[n] = mean_t vox_feats[n, t, 4]
//   out[b, 0, y, x] = 1.0   (occupancy)
//   out[b, 1, y, x] = intensity[n_last]  (last duplicate wins == max n wins)
//
// 2-dispatch structure (votes in ws, disjoint from out, so zero + vote fuse):
//   k1 (one 64-row tile per block, grid = ceil(N/64); 8 VGPR -> full
//       8-blocks/CU residency, wave-level stream overlap):
//       grid-stride zero(out)
//       || tile-coalesced intensity: each wave reads 64 CONSECUTIVE float4s
//          (1 KB contiguous); ch4 elements scatter to unique LDS slots
//          (no atomics, deterministic), 4-lane reduce per row
//       || idempotent max-CAS vote (key = n+1) into ws_vote
//   k2: coherent vote read via atomicAdd(cell,0) (atomic-written data needs
//       an atomic read across dispatches — R3 stale-L2 bug); unique winner
//       plain-stores occ=1.0 + intensity over k1's zeros (verified-safe
//       store-after-store pattern).

#define PX_NY 800
#define PX_NX 700
#define PX_T  32
#define PX_C  5
#define ROW_F4 40                  // float4s per voxel row (160 floats / 4)
#define TILE   64                  // rows per block
#define TILE_F4 (TILE * ROW_F4)    // 2560 float4s per tile
#define LPAD   33                  // padded LDS row stride (floats)

__global__ void __launch_bounds__(256)
pixor_k1(const float4* __restrict__ vox4,
         const int4*   __restrict__ coords4,
         float*        __restrict__ intens,
         unsigned int* __restrict__ vote,
         float4*       __restrict__ out4,
         int N, int P, int zq) {
    __shared__ float lsl[TILE * LPAD];   // [row][t] ch4 values, padded

    const int tid  = threadIdx.x;
    const int gtid = blockIdx.x * 256 + tid;
    const int nth  = gridDim.x * 256;

    // ---- zero the output (contiguous write stream, grid-stride) ----
    const float4 z = make_float4(0.f, 0.f, 0.f, 0.f);
    for (int i = gtid; i < zq; i += nth) out4[i] = z;

    // ---- intensity + vote: exactly one 64-row tile per block ----
    const int t      = blockIdx.x;
    const int base   = t * TILE_F4;
    const int totF4  = N * ROW_F4;

    // load 2560 consecutive float4s; wave = 64 consecutive = 1 KB aligned
#pragma unroll
    for (int k = 0; k < 10; ++k) {
        int i  = k * 256 + tid;           // 0..2559 within tile
        int gi = base + i;
        if (gi < totF4) {
            float4 f = vox4[gi];
            int row = i / ROW_F4;         // 0..63
            int j   = i - row * ROW_F4;   // float4 index within row
            int sub = j % 5;              // 0 -> carries no ch4 element
            if (sub) {
                float v = (sub == 1) ? f.x
                        : (sub == 2) ? f.y
                        : (sub == 3) ? f.z : f.w;
                int tp = (4 * j + (sub - 1) - 4) / 5;   // point idx 0..31
                lsl[row * LPAD + tp] = v; // unique slot: no atomics
            }
        }
    }
    __syncthreads();

    // reduce: 4 lanes per row, 8 values each, then 2-step shuffle
    int row = tid >> 2, q = tid & 3;
    const float* rp = &lsl[row * LPAD + q * 8];
    float s = 0.f;
#pragma unroll
    for (int m = 0; m < 8; ++m) s += rp[m];
    s += __shfl_xor(s, 1);
    s += __shfl_xor(s, 2);

    int grow = t * TILE + row;
    if (q == 0 && grow < N) {
        float inten = s * (1.0f / (float)PX_T);
        intens[grow] = inten;

        int4 c4 = coords4[grow];          // (b, z, y, x)
        unsigned cell = (unsigned)(c4.x * P + c4.z * PX_NX + c4.w);
        unsigned key  = (unsigned)(grow + 1);

        // idempotent max-CAS vote; anything outside [1,N] (0xAA poison,
        // zeros) is garbage and gets replaced; leftover finals are maxima
        unsigned old = atomicCAS(vote + cell, 0u, key);
        while (old != 0u) {
            if ((old - 1u) < (unsigned)N && old >= key) break;
            unsigned prev = atomicCAS(vote + cell, old, key);
            if (prev == old) break;
            old = prev;
        }
    }
}

__global__ void __launch_bounds__(256)
pixor_k2(const int4*   __restrict__ coords4,
         const float*  __restrict__ intens,
         unsigned int* __restrict__ vote,
         float*        __restrict__ out,
         int N, int P) {
    int n = blockIdx.x * 256 + threadIdx.x;
    if (n >= N) return;

    int4 c4 = coords4[n];                 // (b, z, y, x)
    int yx = c4.z * PX_NX + c4.w;
    unsigned cell = (unsigned)(c4.x * P + yx);

    // coherent, non-destructive vote read (leaves buffer idempotent)
    unsigned v = atomicAdd(vote + cell, 0u);
    if (v == (unsigned)(n + 1)) {         // unique winner
        int base = c4.x * (2 * P) + yx;
        out[base]     = 1.0f;             // occupancy
        out[base + P] = intens[n];        // intensity
    }
}

extern "C" void kernel_launch(void* const* d_in, const int* in_sizes, int n_in,
                              void* d_out, int out_size, void* d_ws, size_t ws_size,
                              hipStream_t stream) {
    const float* vox    = (const float*)d_in[0];   // [N, 32, 5] f32
    const int*   coords = (const int*)d_in[2];     // [N, 4] i32 (b, z, y, x)
    float* out = (float*)d_out;

    const int N  = in_sizes[1];                    // 200000
    const int P  = PX_NY * PX_NX;                  // 560000
    const int B  = out_size / (2 * P);             // 16
    const int zq = out_size / 4;                   // float4s to zero

    unsigned int* ws_vote = (unsigned int*)d_ws;             // B*P uints
    float*        ws_int  = (float*)d_ws + (size_t)B * P;    // N floats

    const int BLK = 256;
    const int ntiles = (N + TILE - 1) / TILE;      // 3125: one tile per block

    pixor_k1<<<ntiles, BLK, 0, stream>>>((const float4*)vox, (const int4*)coords,
                                         ws_int, ws_vote, (float4*)out,
                                         N, P, zq);

    pixor_k2<<<(N + BLK - 1) / BLK, BLK, 0, stream>>>((const int4*)coords,
                                                      ws_int, ws_vote, out,
                                                      N, P);
}